// Round 20
// baseline (711.657 us; speedup 1.0000x reference)
//
#include <hip/hip_runtime.h>
#include <math.h>

// DenseCRF mean-field on MI355X. N=9216, C=21, 5 iters.
// R20: hide the smoothness chain inside the bilateral dispatch. smo_y+smo_x
// fused into one plane-per-block path (y-conv -> 36KB LDS plane -> x-conv),
// run as blocks 0..20 of the bilateral dispatch (21 blocks = 1.2% of grid,
// ~6us each, hidden under the 48us bilateral). LDS 37.6KB still allows the
// register-capped 4 blocks/CU. Bilateral body + combine = R19 verbatim.

#define NN 9216
#define CC 21
#define HH 96
#define WW 96
#define CP 24            // unary channel stride (f32)
#define JS2 12           // j-slices
#define NJ2 (NN / JS2)   // 768 j per slice
#define TJ2 128          // shared j tile (4 ks-slices of 32)
#define OST2 136         // LDS out^T row stride in f16
#define NBIL (144 * JS2) // 1728 bilateral blocks

typedef _Float16 half8 __attribute__((ext_vector_type(8)));
typedef __fp16 fp16x2 __attribute__((ext_vector_type(2)));
typedef float f32x4 __attribute__((ext_vector_type(4)));

union HU { int i[4]; half8 h; };

// ---------------- fused features + initial softmax ------------------------
__global__ __launch_bounds__(256) void featinit_kernel(const float* __restrict__ x,
                                                       const float* __restrict__ yhat,
                                                       float* __restrict__ feat,
                                                       float* __restrict__ unary,
                                                       _Float16* __restrict__ out_hi,
                                                       _Float16* __restrict__ out_lo,
                                                       float* __restrict__ out_cn) {
    int n = blockIdx.x * 256 + threadIdx.x;
    {
        int y = n / WW, xx = n - y * WW;
        const float inv_sqrt_ln2 = 1.2011224087864498f;
        float sp = inv_sqrt_ln2 / 30.0f;
        float sc = inv_sqrt_ln2 * 10.0f;
        float fy = (float)y * sp;
        float fx = (float)xx * sp;
        float fr = x[0 * NN + n] * sc;
        float fg = x[1 * NN + n] * sc;
        float fb = x[2 * NN + n] * sc;
        float S = fy * fy + fx * fx + fr * fr + fg * fg + fb * fb;
        float4* f4 = (float4*)(feat + (size_t)n * 8);
        f4[0] = make_float4(fy, fx, fr, fg);
        f4[1] = make_float4(fb, -0.5f * S, 0.0f, 0.0f);
    }
    float u[CC], p[CC];
    float m = -1e30f;
#pragma unroll
    for (int c = 0; c < CC; c++) { u[c] = yhat[c * NN + n]; m = fmaxf(m, u[c]); }
    float s = 0.0f;
#pragma unroll
    for (int c = 0; c < CC; c++) { p[c] = __expf(u[c] - m); s += p[c]; }
    float inv = 1.0f / s;
#pragma unroll
    for (int c = 0; c < CC; c++) p[c] *= inv;
#pragma unroll
    for (int c = 0; c < CC; c++) {
        unary[n * CP + c] = u[c];
        _Float16 ph = (_Float16)p[c];
        out_hi[(size_t)c * NN + n] = ph;
        out_lo[(size_t)c * NN + n] = (_Float16)(p[c] - (float)ph);
        out_cn[c * NN + n] = p[c];
    }
#pragma unroll
    for (int c = CC; c < CP; c++) {
        unary[n * CP + c] = 0.0f;
        out_hi[(size_t)c * NN + n] = (_Float16)0.0f;
        out_lo[(size_t)c * NN + n] = (_Float16)0.0f;
    }
}

// ---------------- fused bilateral (blocks 21..1748) + smo (blocks 0..20) --
// Bilateral: 64 i's (4 i-tiles of 16), shared 128-j LDS tile, wave w =
// ks-slice w. 6 rounds. part[k][n][32]. Smo: one channel plane per block,
// y-conv -> LDS plane -> x-conv (identical math to old smo_y/smo_x).
__global__ __launch_bounds__(256, 4) void bilateral_smo(const float* __restrict__ feat,
                                                        const _Float16* __restrict__ out_hi,
                                                        const _Float16* __restrict__ out_lo,
                                                        float* __restrict__ part,
                                                        const float* __restrict__ out_cn,
                                                        float* __restrict__ smo) {
    __shared__ float smem[9408];                        // 37632 B (plane + wt)
    const int tid = threadIdx.x;
    int bid = blockIdx.x;

    if (bid < CC) {
        // ---------------- smoothness: full separable conv for channel bid
        const int c = bid;
        float* plane = smem;                            // [9216] y-conv result
        float* wt = smem + 9216;                        // [191]
        if (tid < 2 * HH - 1) {
            float d = (float)(tid - (HH - 1));
            wt[tid] = __expf(d * d * (-1.0f / 18.0f));
        }
        __syncthreads();
#pragma unroll 1
        for (int k = 0; k < 36; ++k) {
            int n = k * 256 + tid;
            int y = n / WW, x = n - y * WW;
            const float* s = out_cn + (size_t)c * NN + x;
            float a = 0.0f;
            for (int yp = 0; yp < HH; yp++) a = fmaf(wt[yp - y + (HH - 1)], s[yp * WW], a);
            plane[n] = a;
        }
        __syncthreads();
#pragma unroll 1
        for (int k = 0; k < 36; ++k) {
            int n = k * 256 + tid;
            int y = n / WW, x = n - y * WW;
            const float* s = plane + y * WW;
            float a = 0.0f;
            for (int xp = 0; xp < WW; xp++) a = fmaf(wt[xp - x + (HH - 1)], s[xp], a);
            smo[(size_t)c * NN + n] = a;
        }
        return;
    }
    bid -= CC;

    // ---------------- bilateral via split-f16 MFMA (R19 verbatim) ---------
    float* sfeat = smem;                                // [128 j][8] f32, swizzled
    _Float16* sh_ = (_Float16*)(smem + 1024);           // [24 c][OST2] f16 hi
    _Float16* sl_ = (_Float16*)(smem + 2656);           // [24 c][OST2] f16 lo

    const int lane = tid & 63;
    const int w = tid >> 6;
    const int r = lane & 15;       // A-row / B-col / D-col index
    const int g = lane >> 4;       // k-group
    const int i0 = (bid % 144) * 64;
    const int jslice = (bid / 144) * NJ2;

    float fi0[4], fi1[4], fi2[4], fi3[4], fi4[4], hsi[4];
#pragma unroll
    for (int m = 0; m < 4; ++m) {
        const float* fp = feat + (size_t)(i0 + m * 16 + r) * 8;
        float4 A = *(const float4*)fp;
        float2 B = *(const float2*)(fp + 4);
        fi0[m] = A.x; fi1[m] = A.y; fi2[m] = A.z; fi3[m] = A.w;
        fi4[m] = B.x; hsi[m] = B.y;
    }

    f32x4 acc[4][2];
#pragma unroll
    for (int m = 0; m < 4; ++m) { acc[m][0] = (f32x4)0.0f; acc[m][1] = (f32x4)0.0f; }

    const int jb = w * 32 + g * 8;             // lane's 8 j's (k-dim), f16 idx
    const int r2 = (r < 8) ? (16 + r) : 23;    // clamp to zero row

#pragma unroll 1
    for (int rd = 0; rd < NJ2 / TJ2; ++rd) {   // 6 rounds
        __syncthreads();
        // stage j-features, swizzled: 128 j x 2 float4 = 256 chunks (1/thread)
        {
            int j = tid >> 1, h = tid & 1;
            int jp = j ^ ((j >> 3) & 3);
            ((float4*)sfeat)[jp * 2 + h] =
                *(const float4*)(feat + (size_t)(jslice + rd * TJ2 + j) * 8 + h * 4);
        }
        // stage out hi+lo: 2 arrays x 24 c x 16 chunks = 768
        for (int v = tid; v < 768; v += 256) {
            int vv = v;
            _Float16* dstbase;
            const _Float16* srcbase;
            if (vv < 384) { dstbase = sh_; srcbase = out_hi; }
            else { dstbase = sl_; srcbase = out_lo; vv -= 384; }
            int c = vv >> 4, j8 = vv & 15;
            *(float4*)(dstbase + c * OST2 + j8 * 8) =
                *(const float4*)(srcbase + (size_t)c * NN + jslice + rd * TJ2 + j8 * 8);
        }
        __syncthreads();

        // A-fragments, t-major; packed K words assembled from cvt_pkrtz.
        // Physical slot base+(t^g) holds LOGICAL j = base+t.
        int wh[4][4], wl[4][4];                // [m][tp], fully static
#pragma unroll
        for (int tp = 0; tp < 4; ++tp) {
            const float* jp0 = sfeat + (size_t)(w * 32 + g * 8 + ((2 * tp) ^ g)) * 8;
            const float* jp1 = sfeat + (size_t)(w * 32 + g * 8 + ((2 * tp + 1) ^ g)) * 8;
            float4 A0 = *(const float4*)jp0;
            float2 B0 = *(const float2*)(jp0 + 4);
            float4 A1 = *(const float4*)jp1;
            float2 B1 = *(const float2*)(jp1 + 4);
#pragma unroll
            for (int m = 0; m < 4; ++m) {
                float d0 = hsi[m] + B0.y;
                d0 = fmaf(fi0[m], A0.x, d0);
                d0 = fmaf(fi1[m], A0.y, d0);
                d0 = fmaf(fi2[m], A0.z, d0);
                d0 = fmaf(fi3[m], A0.w, d0);
                d0 = fmaf(fi4[m], B0.x, d0);
                float d1 = hsi[m] + B1.y;
                d1 = fmaf(fi0[m], A1.x, d1);
                d1 = fmaf(fi1[m], A1.y, d1);
                d1 = fmaf(fi2[m], A1.z, d1);
                d1 = fmaf(fi3[m], A1.w, d1);
                d1 = fmaf(fi4[m], B1.x, d1);
                float k0 = __builtin_amdgcn_exp2f(d0);
                float k1 = __builtin_amdgcn_exp2f(d1);
                fp16x2 kh = __builtin_amdgcn_cvt_pkrtz(k0, k1);
                fp16x2 kl = __builtin_amdgcn_cvt_pkrtz(k0 - (float)kh.x,
                                                       k1 - (float)kh.y);
                __builtin_memcpy(&wh[m][tp], &kh, 4);
                __builtin_memcpy(&wl[m][tp], &kl, 4);
            }
        }
        half8 b0h = *(const half8*)(sh_ + r * OST2 + jb);
        half8 b0l = *(const half8*)(sl_ + r * OST2 + jb);
        half8 b1h = *(const half8*)(sh_ + r2 * OST2 + jb);
        half8 b1l = *(const half8*)(sl_ + r2 * OST2 + jb);
#pragma unroll
        for (int m = 0; m < 4; ++m) {
            HU uh, ul;
            uh.i[0] = wh[m][0]; uh.i[1] = wh[m][1];
            uh.i[2] = wh[m][2]; uh.i[3] = wh[m][3];
            ul.i[0] = wl[m][0]; ul.i[1] = wl[m][1];
            ul.i[2] = wl[m][2]; ul.i[3] = wl[m][3];
            acc[m][0] = __builtin_amdgcn_mfma_f32_16x16x32_f16(uh.h, b0h, acc[m][0], 0, 0, 0);
            acc[m][0] = __builtin_amdgcn_mfma_f32_16x16x32_f16(ul.h, b0h, acc[m][0], 0, 0, 0);
            acc[m][0] = __builtin_amdgcn_mfma_f32_16x16x32_f16(uh.h, b0l, acc[m][0], 0, 0, 0);
            acc[m][1] = __builtin_amdgcn_mfma_f32_16x16x32_f16(uh.h, b1h, acc[m][1], 0, 0, 0);
            acc[m][1] = __builtin_amdgcn_mfma_f32_16x16x32_f16(ul.h, b1h, acc[m][1], 0, 0, 0);
            acc[m][1] = __builtin_amdgcn_mfma_f32_16x16x32_f16(uh.h, b1l, acc[m][1], 0, 0, 0);
        }
    }

    // 4-phase cross-wave reduce — fully unrolled (static acc indices)
#pragma unroll
    for (int m = 0; m < 4; ++m) {
        __syncthreads();
        if (w != m) {
            float* dst = smem + (size_t)(w * 64 + lane) * 12;
            *(f32x4*)(dst + 0) = acc[m][0];
            *(f32x4*)(dst + 4) = acc[m][1];
        }
        __syncthreads();
        if (w == m) {
            f32x4 s0 = acc[m][0], s1 = acc[m][1];
#pragma unroll
            for (int k = 0; k < 4; ++k) {
                if (k == m) continue;
                const float* src = smem + (size_t)(k * 64 + lane) * 12;
                s0 += *(const f32x4*)(src + 0);
                s1 += *(const f32x4*)(src + 4);
            }
            // D layout: i = i0 + m*16 + g*4 + q, class = {r, 16+r}
            float* pb = part + ((size_t)(bid / 144) * NN + i0 + m * 16 + g * 4) * 32 + r;
#pragma unroll
            for (int q = 0; q < 4; ++q) {
                pb[q * 32] = s0[q];
                pb[q * 32 + 16] = s1[q];
            }
        }
    }
}

// ---------------- combine: coalesced k-reduce + mu + softmax --------------
__global__ __launch_bounds__(256) void combine_kernel(const float* __restrict__ part,
                                                      const float* __restrict__ smo,
                                                      const float* __restrict__ mu,
                                                      float* __restrict__ unary,
                                                      _Float16* __restrict__ out_hi,
                                                      _Float16* __restrict__ out_lo,
                                                      float* __restrict__ out_cn) {
    __shared__ float muL[CC * CC];
    __shared__ float app[256 * 33];
    int tid = threadIdx.x;
    for (int u = tid; u < CC * CC; u += 256) muL[u] = mu[u];
    const int n0 = blockIdx.x * 256;

    // coalesced k-reduction: 8 float4 slots per thread (v, v+256, ...)
    f32x4 a[8];
#pragma unroll
    for (int s8 = 0; s8 < 8; ++s8) a[s8] = (f32x4)0.0f;
#pragma unroll 1
    for (int k = 0; k < JS2; ++k) {
        const float* base = part + (size_t)k * NN * 32 + (size_t)n0 * 32;
#pragma unroll
        for (int s8 = 0; s8 < 8; ++s8) {
            a[s8] += *(const f32x4*)(base + (size_t)(s8 * 256 + tid) * 4);
        }
    }
#pragma unroll
    for (int s8 = 0; s8 < 8; ++s8) {
        int v = s8 * 256 + tid;
        int nl = v >> 3, c4 = v & 7;
        float* dst = app + nl * 33 + c4 * 4;
        dst[0] = a[s8][0]; dst[1] = a[s8][1]; dst[2] = a[s8][2]; dst[3] = a[s8][3];
    }
    __syncthreads();

    int n = n0 + tid;
    float pin[CC];
#pragma unroll
    for (int c = 0; c < CC; c++)
        pin[c] = 10.0f * app[tid * 33 + c] + 3.0f * smo[c * NN + n];
    float pout[CC];
#pragma unroll
    for (int j = 0; j < CC; j++) pout[j] = 0.0f;
#pragma unroll
    for (int i2 = 0; i2 < CC; i2++) {
        float v = pin[i2];
#pragma unroll
        for (int j = 0; j < CC; j++) pout[j] = fmaf(v, muL[i2 * CC + j], pout[j]);
    }
    float u[CC], p[CC];
    float m = -1e30f;
#pragma unroll
    for (int c = 0; c < CC; c++) {
        u[c] = unary[n * CP + c] + pout[c];
        m = fmaxf(m, u[c]);
    }
    float s = 0.0f;
#pragma unroll
    for (int c = 0; c < CC; c++) { p[c] = __expf(u[c] - m); s += p[c]; }
    float inv = 1.0f / s;
#pragma unroll
    for (int c = 0; c < CC; c++) p[c] *= inv;
#pragma unroll
    for (int c = 0; c < CC; c++) {
        unary[n * CP + c] = u[c];
        _Float16 ph = (_Float16)p[c];
        out_hi[(size_t)c * NN + n] = ph;
        out_lo[(size_t)c * NN + n] = (_Float16)(p[c] - (float)ph);
        out_cn[c * NN + n] = p[c];
    }
}

extern "C" void kernel_launch(void* const* d_in, const int* in_sizes, int n_in,
                              void* d_out, int out_size, void* d_ws, size_t ws_size,
                              hipStream_t stream) {
    const float* x = (const float*)d_in[0];     // (3,96,96)
    const float* yhat = (const float*)d_in[1];  // (21,96,96)
    const float* mu = (const float*)d_in[2];    // (21,21)
    float* out = (float*)d_out;                 // (21,96,96) c-major probs
    float* ws = (float*)d_ws;

    float*     feat   = ws;                         // 8*N            = 73728 f32
    _Float16*  out_hi = (_Float16*)(ws + 73728);    // 24*N f16       = 110592 f32-eq
    _Float16*  out_lo = (_Float16*)(ws + 184320);   // 24*N f16       = 110592 f32-eq
    float*     unary  = ws + 294912;                // 24*N           = 221184
    float*     smo    = ws + 516096;                // 21*N           = 193536
    float*     tmp    = ws + 709632;                // 21*N (unused)
    float*     part   = ws + 903168;                // JS2*N*32       = 3538944 (~17.8MB total)
    (void)tmp;

    featinit_kernel<<<NN / 256, 256, 0, stream>>>(x, yhat, feat, unary, out_hi, out_lo, out);

    for (int it = 0; it < 5; it++) {
        bilateral_smo<<<NBIL + CC, 256, 0, stream>>>(feat, out_hi, out_lo, part, out, smo);
        combine_kernel<<<NN / 256, 256, 0, stream>>>(part, smo, mu, unary, out_hi, out_lo, out);
    }
}

// Round 21
// 351.222 us; speedup vs baseline: 2.0262x; 2.0262x over previous
//
#include <hip/hip_runtime.h>
#include <math.h>

// DenseCRF mean-field on MI355X. N=9216, C=21, 5 iters.
// R21: restore R19 verbatim (best proven: 352us). R20's plane-per-block smo
// fusion REVERTED — 21 fat blocks exposed ~80us of serial conv latency that
// 756 thin blocks hide via TLP (3rd failed heterogeneous fusion: R12/R18/R20).
// Structure: bilateral split-f16 3-MFMA (JS2=12, 6 rounds, cap 4, 48.6us) +
// smo_y/smo_x natural-width + coalesced two-stage combine.

#define NN 9216
#define CC 21
#define HH 96
#define WW 96
#define CP 24            // unary channel stride (f32)
#define JS2 12           // j-slices
#define NJ2 (NN / JS2)   // 768 j per slice
#define TJ2 128          // shared j tile (4 ks-slices of 32)
#define OST2 136         // LDS out^T row stride in f16

typedef _Float16 half8 __attribute__((ext_vector_type(8)));
typedef __fp16 fp16x2 __attribute__((ext_vector_type(2)));
typedef float f32x4 __attribute__((ext_vector_type(4)));

union HU { int i[4]; half8 h; };

// ---------------- fused features + initial softmax ------------------------
__global__ __launch_bounds__(256) void featinit_kernel(const float* __restrict__ x,
                                                       const float* __restrict__ yhat,
                                                       float* __restrict__ feat,
                                                       float* __restrict__ unary,
                                                       _Float16* __restrict__ out_hi,
                                                       _Float16* __restrict__ out_lo,
                                                       float* __restrict__ out_cn) {
    int n = blockIdx.x * 256 + threadIdx.x;
    {
        int y = n / WW, xx = n - y * WW;
        const float inv_sqrt_ln2 = 1.2011224087864498f;
        float sp = inv_sqrt_ln2 / 30.0f;
        float sc = inv_sqrt_ln2 * 10.0f;
        float fy = (float)y * sp;
        float fx = (float)xx * sp;
        float fr = x[0 * NN + n] * sc;
        float fg = x[1 * NN + n] * sc;
        float fb = x[2 * NN + n] * sc;
        float S = fy * fy + fx * fx + fr * fr + fg * fg + fb * fb;
        float4* f4 = (float4*)(feat + (size_t)n * 8);
        f4[0] = make_float4(fy, fx, fr, fg);
        f4[1] = make_float4(fb, -0.5f * S, 0.0f, 0.0f);
    }
    float u[CC], p[CC];
    float m = -1e30f;
#pragma unroll
    for (int c = 0; c < CC; c++) { u[c] = yhat[c * NN + n]; m = fmaxf(m, u[c]); }
    float s = 0.0f;
#pragma unroll
    for (int c = 0; c < CC; c++) { p[c] = __expf(u[c] - m); s += p[c]; }
    float inv = 1.0f / s;
#pragma unroll
    for (int c = 0; c < CC; c++) p[c] *= inv;
#pragma unroll
    for (int c = 0; c < CC; c++) {
        unary[n * CP + c] = u[c];
        _Float16 ph = (_Float16)p[c];
        out_hi[(size_t)c * NN + n] = ph;
        out_lo[(size_t)c * NN + n] = (_Float16)(p[c] - (float)ph);
        out_cn[c * NN + n] = p[c];
    }
#pragma unroll
    for (int c = CC; c < CP; c++) {
        unary[n * CP + c] = 0.0f;
        out_hi[(size_t)c * NN + n] = (_Float16)0.0f;
        out_lo[(size_t)c * NN + n] = (_Float16)0.0f;
    }
}

// ---------------- bilateral via split-f16 MFMA ----------------------------
// grid (144, 12). Block: 64 i's (4 i-tiles of 16); shared 128-j LDS tile per
// round, wave w consumes ks-slice w (32 j). 6 rounds. part[k][n][32].
__global__ __launch_bounds__(256, 4) void bilateral_mfma(const float* __restrict__ feat,
                                                         const _Float16* __restrict__ out_hi,
                                                         const _Float16* __restrict__ out_lo,
                                                         float* __restrict__ part) {
    __shared__ float smemf[4288];                       // 17152 B
    float* sfeat = smemf;                               // [128 j][8] f32, swizzled
    _Float16* sh_ = (_Float16*)(smemf + 1024);          // [24 c][OST2] f16 hi
    _Float16* sl_ = (_Float16*)(smemf + 2656);          // [24 c][OST2] f16 lo

    const int tid = threadIdx.x;
    const int lane = tid & 63;
    const int w = tid >> 6;
    const int r = lane & 15;       // A-row / B-col / D-col index
    const int g = lane >> 4;       // k-group
    const int i0 = blockIdx.x * 64;
    const int jslice = blockIdx.y * NJ2;

    float fi0[4], fi1[4], fi2[4], fi3[4], fi4[4], hsi[4];
#pragma unroll
    for (int m = 0; m < 4; ++m) {
        const float* fp = feat + (size_t)(i0 + m * 16 + r) * 8;
        float4 A = *(const float4*)fp;
        float2 B = *(const float2*)(fp + 4);
        fi0[m] = A.x; fi1[m] = A.y; fi2[m] = A.z; fi3[m] = A.w;
        fi4[m] = B.x; hsi[m] = B.y;
    }

    f32x4 acc[4][2];
#pragma unroll
    for (int m = 0; m < 4; ++m) { acc[m][0] = (f32x4)0.0f; acc[m][1] = (f32x4)0.0f; }

    const int jb = w * 32 + g * 8;             // lane's 8 j's (k-dim), f16 idx
    const int r2 = (r < 8) ? (16 + r) : 23;    // clamp to zero row

#pragma unroll 1
    for (int rd = 0; rd < NJ2 / TJ2; ++rd) {   // 6 rounds
        __syncthreads();
        // stage j-features, swizzled: 128 j x 2 float4 = 256 chunks (1/thread)
        {
            int j = tid >> 1, h = tid & 1;
            int jp = j ^ ((j >> 3) & 3);
            ((float4*)sfeat)[jp * 2 + h] =
                *(const float4*)(feat + (size_t)(jslice + rd * TJ2 + j) * 8 + h * 4);
        }
        // stage out hi+lo: 2 arrays x 24 c x 16 chunks = 768
        for (int v = tid; v < 768; v += 256) {
            int vv = v;
            _Float16* dstbase;
            const _Float16* srcbase;
            if (vv < 384) { dstbase = sh_; srcbase = out_hi; }
            else { dstbase = sl_; srcbase = out_lo; vv -= 384; }
            int c = vv >> 4, j8 = vv & 15;
            *(float4*)(dstbase + c * OST2 + j8 * 8) =
                *(const float4*)(srcbase + (size_t)c * NN + jslice + rd * TJ2 + j8 * 8);
        }
        __syncthreads();

        // A-fragments, t-major; packed K words assembled from cvt_pkrtz.
        // Physical slot base+(t^g) holds LOGICAL j = base+t.
        int wh[4][4], wl[4][4];                // [m][tp], fully static
#pragma unroll
        for (int tp = 0; tp < 4; ++tp) {
            const float* jp0 = sfeat + (size_t)(w * 32 + g * 8 + ((2 * tp) ^ g)) * 8;
            const float* jp1 = sfeat + (size_t)(w * 32 + g * 8 + ((2 * tp + 1) ^ g)) * 8;
            float4 A0 = *(const float4*)jp0;
            float2 B0 = *(const float2*)(jp0 + 4);
            float4 A1 = *(const float4*)jp1;
            float2 B1 = *(const float2*)(jp1 + 4);
#pragma unroll
            for (int m = 0; m < 4; ++m) {
                float d0 = hsi[m] + B0.y;
                d0 = fmaf(fi0[m], A0.x, d0);
                d0 = fmaf(fi1[m], A0.y, d0);
                d0 = fmaf(fi2[m], A0.z, d0);
                d0 = fmaf(fi3[m], A0.w, d0);
                d0 = fmaf(fi4[m], B0.x, d0);
                float d1 = hsi[m] + B1.y;
                d1 = fmaf(fi0[m], A1.x, d1);
                d1 = fmaf(fi1[m], A1.y, d1);
                d1 = fmaf(fi2[m], A1.z, d1);
                d1 = fmaf(fi3[m], A1.w, d1);
                d1 = fmaf(fi4[m], B1.x, d1);
                float k0 = __builtin_amdgcn_exp2f(d0);
                float k1 = __builtin_amdgcn_exp2f(d1);
                fp16x2 kh = __builtin_amdgcn_cvt_pkrtz(k0, k1);
                fp16x2 kl = __builtin_amdgcn_cvt_pkrtz(k0 - (float)kh.x,
                                                       k1 - (float)kh.y);
                __builtin_memcpy(&wh[m][tp], &kh, 4);
                __builtin_memcpy(&wl[m][tp], &kl, 4);
            }
        }
        half8 b0h = *(const half8*)(sh_ + r * OST2 + jb);
        half8 b0l = *(const half8*)(sl_ + r * OST2 + jb);
        half8 b1h = *(const half8*)(sh_ + r2 * OST2 + jb);
        half8 b1l = *(const half8*)(sl_ + r2 * OST2 + jb);
#pragma unroll
        for (int m = 0; m < 4; ++m) {
            HU uh, ul;
            uh.i[0] = wh[m][0]; uh.i[1] = wh[m][1];
            uh.i[2] = wh[m][2]; uh.i[3] = wh[m][3];
            ul.i[0] = wl[m][0]; ul.i[1] = wl[m][1];
            ul.i[2] = wl[m][2]; ul.i[3] = wl[m][3];
            acc[m][0] = __builtin_amdgcn_mfma_f32_16x16x32_f16(uh.h, b0h, acc[m][0], 0, 0, 0);
            acc[m][0] = __builtin_amdgcn_mfma_f32_16x16x32_f16(ul.h, b0h, acc[m][0], 0, 0, 0);
            acc[m][0] = __builtin_amdgcn_mfma_f32_16x16x32_f16(uh.h, b0l, acc[m][0], 0, 0, 0);
            acc[m][1] = __builtin_amdgcn_mfma_f32_16x16x32_f16(uh.h, b1h, acc[m][1], 0, 0, 0);
            acc[m][1] = __builtin_amdgcn_mfma_f32_16x16x32_f16(ul.h, b1h, acc[m][1], 0, 0, 0);
            acc[m][1] = __builtin_amdgcn_mfma_f32_16x16x32_f16(uh.h, b1l, acc[m][1], 0, 0, 0);
        }
    }

    // 4-phase cross-wave reduce — fully unrolled (static acc indices)
#pragma unroll
    for (int m = 0; m < 4; ++m) {
        __syncthreads();
        if (w != m) {
            float* dst = smemf + (size_t)(w * 64 + lane) * 12;
            *(f32x4*)(dst + 0) = acc[m][0];
            *(f32x4*)(dst + 4) = acc[m][1];
        }
        __syncthreads();
        if (w == m) {
            f32x4 s0 = acc[m][0], s1 = acc[m][1];
#pragma unroll
            for (int k = 0; k < 4; ++k) {
                if (k == m) continue;
                const float* src = smemf + (size_t)(k * 64 + lane) * 12;
                s0 += *(const f32x4*)(src + 0);
                s1 += *(const f32x4*)(src + 4);
            }
            // D layout: i = i0 + m*16 + g*4 + q, class = {r, 16+r}
            float* pb = part + ((size_t)blockIdx.y * NN + i0 + m * 16 + g * 4) * 32 + r;
#pragma unroll
            for (int q = 0; q < 4; ++q) {
                pb[q * 32] = s0[q];
                pb[q * 32 + 16] = s1[q];
            }
        }
    }
}

// ---------------- separable smoothness conv (exact, full width) -----------
__global__ __launch_bounds__(256) void smo_y_kernel(const float* __restrict__ src,
                                                    float* __restrict__ dst) {
    __shared__ float wt[2 * HH - 1];
    int tid = threadIdx.x;
    if (tid < 2 * HH - 1) {
        float d = (float)(tid - (HH - 1));
        wt[tid] = __expf(d * d * (-1.0f / 18.0f));
    }
    __syncthreads();
    int id = blockIdx.x * 256 + tid;       // c*NN + y*WW + x
    int c = id / NN;
    int rem = id - c * NN;
    int y = rem / WW;
    int x = rem - y * WW;
    const float* s = src + (size_t)c * NN + x;
    float a = 0.0f;
    for (int yp = 0; yp < HH; yp++) a = fmaf(wt[yp - y + (HH - 1)], s[yp * WW], a);
    dst[id] = a;
}

__global__ __launch_bounds__(256) void smo_x_kernel(const float* __restrict__ src,
                                                    float* __restrict__ dst) {
    __shared__ float wt[2 * HH - 1];
    int tid = threadIdx.x;
    if (tid < 2 * HH - 1) {
        float d = (float)(tid - (HH - 1));
        wt[tid] = __expf(d * d * (-1.0f / 18.0f));
    }
    __syncthreads();
    int id = blockIdx.x * 256 + tid;
    int c = id / NN;
    int rem = id - c * NN;
    int y = rem / WW;
    int x = rem - y * WW;
    const float* s = src + (size_t)c * NN + y * WW;
    float a = 0.0f;
    for (int xp = 0; xp < WW; xp++) a = fmaf(wt[xp - x + (HH - 1)], s[xp], a);
    dst[id] = a;
}

// ---------------- combine: coalesced k-reduce + mu + softmax --------------
// Block = 256 pixels. Stage 1: threads read part[k][n][32] as contiguous
// float4 spans (v = n_local*8 + c4), accumulate over k in registers, dump to
// padded LDS app[n][33]. Stage 2: per-thread mu transform + softmax.
__global__ __launch_bounds__(256) void combine_kernel(const float* __restrict__ part,
                                                      const float* __restrict__ smo,
                                                      const float* __restrict__ mu,
                                                      float* __restrict__ unary,
                                                      _Float16* __restrict__ out_hi,
                                                      _Float16* __restrict__ out_lo,
                                                      float* __restrict__ out_cn) {
    __shared__ float muL[CC * CC];
    __shared__ float app[256 * 33];
    int tid = threadIdx.x;
    for (int u = tid; u < CC * CC; u += 256) muL[u] = mu[u];
    const int n0 = blockIdx.x * 256;

    // coalesced k-reduction: 8 float4 slots per thread (v, v+256, ...)
    f32x4 a[8];
#pragma unroll
    for (int s8 = 0; s8 < 8; ++s8) a[s8] = (f32x4)0.0f;
#pragma unroll 1
    for (int k = 0; k < JS2; ++k) {
        const float* base = part + (size_t)k * NN * 32 + (size_t)n0 * 32;
#pragma unroll
        for (int s8 = 0; s8 < 8; ++s8) {
            a[s8] += *(const f32x4*)(base + (size_t)(s8 * 256 + tid) * 4);
        }
    }
#pragma unroll
    for (int s8 = 0; s8 < 8; ++s8) {
        int v = s8 * 256 + tid;
        int nl = v >> 3, c4 = v & 7;
        float* dst = app + nl * 33 + c4 * 4;
        dst[0] = a[s8][0]; dst[1] = a[s8][1]; dst[2] = a[s8][2]; dst[3] = a[s8][3];
    }
    __syncthreads();

    int n = n0 + tid;
    float pin[CC];
#pragma unroll
    for (int c = 0; c < CC; c++)
        pin[c] = 10.0f * app[tid * 33 + c] + 3.0f * smo[c * NN + n];
    float pout[CC];
#pragma unroll
    for (int j = 0; j < CC; j++) pout[j] = 0.0f;
#pragma unroll
    for (int i2 = 0; i2 < CC; i2++) {
        float v = pin[i2];
#pragma unroll
        for (int j = 0; j < CC; j++) pout[j] = fmaf(v, muL[i2 * CC + j], pout[j]);
    }
    float u[CC], p[CC];
    float m = -1e30f;
#pragma unroll
    for (int c = 0; c < CC; c++) {
        u[c] = unary[n * CP + c] + pout[c];
        m = fmaxf(m, u[c]);
    }
    float s = 0.0f;
#pragma unroll
    for (int c = 0; c < CC; c++) { p[c] = __expf(u[c] - m); s += p[c]; }
    float inv = 1.0f / s;
#pragma unroll
    for (int c = 0; c < CC; c++) p[c] *= inv;
#pragma unroll
    for (int c = 0; c < CC; c++) {
        unary[n * CP + c] = u[c];
        _Float16 ph = (_Float16)p[c];
        out_hi[(size_t)c * NN + n] = ph;
        out_lo[(size_t)c * NN + n] = (_Float16)(p[c] - (float)ph);
        out_cn[c * NN + n] = p[c];
    }
}

extern "C" void kernel_launch(void* const* d_in, const int* in_sizes, int n_in,
                              void* d_out, int out_size, void* d_ws, size_t ws_size,
                              hipStream_t stream) {
    const float* x = (const float*)d_in[0];     // (3,96,96)
    const float* yhat = (const float*)d_in[1];  // (21,96,96)
    const float* mu = (const float*)d_in[2];    // (21,21)
    float* out = (float*)d_out;                 // (21,96,96) c-major probs
    float* ws = (float*)d_ws;

    float*     feat   = ws;                         // 8*N            = 73728 f32
    _Float16*  out_hi = (_Float16*)(ws + 73728);    // 24*N f16       = 110592 f32-eq
    _Float16*  out_lo = (_Float16*)(ws + 184320);   // 24*N f16       = 110592 f32-eq
    float*     unary  = ws + 294912;                // 24*N           = 221184
    float*     smo    = ws + 516096;                // 21*N           = 193536
    float*     tmp    = ws + 709632;                // 21*N           = 193536
    float*     part   = ws + 903168;                // JS2*N*32       = 3538944 (~17.8MB total)

    featinit_kernel<<<NN / 256, 256, 0, stream>>>(x, yhat, feat, unary, out_hi, out_lo, out);

    for (int it = 0; it < 5; it++) {
        bilateral_mfma<<<dim3(144, JS2), 256, 0, stream>>>(feat, out_hi, out_lo, part);
        smo_y_kernel<<<CC * NN / 256, 256, 0, stream>>>(out, tmp);
        smo_x_kernel<<<CC * NN / 256, 256, 0, stream>>>(tmp, smo);
        combine_kernel<<<NN / 256, 256, 0, stream>>>(part, smo, mu, unary, out_hi, out_lo, out);
    }
}